// Round 3
// baseline (348.246 us; speedup 1.0000x reference)
//
#include <hip/hip_runtime.h>
#include <math.h>

// ============================================================================
// EnhancedGrayscaleCombinedLoss: 0.3 * L2 + 0.7 * (1 - MS-SSIM(3 scales))
// B=64, C=1, H=176, W=1008 fp32. Out: [total, l2, ssim_loss].
// scale0: win 11x15 pad(5,7) out 176x1008 ; scale1: 9x12 pad(4,6) out 88x505 ;
// scale2: 7x10 pad(3,5) out 44x253. Window separable: outer(gh, gw).
//
// R2 design:
//  - v-conv FIRST (direct global float4 taps, no LDS input staging),
//    5 SoA planes in LDS (25.6KB), h-conv via ds_read_b128 (4 cols/thread).
//  - Gaussian windows computed per-thread with expf -> readlane -> SGPRs.
//  - kernelA = ssim0 blocks + pool blocks (overlap HBM pool w/ VALU ssim;
//    L2 loss folded into ssim0 center tap). kernelB = ssim1+ssim2. kernelC=final.
//  - Per-block SoA partials, no atomics, no memset.
// ============================================================================

constexpr int NPOOL = 1024;
constexpr int NS0 = 16 * 11 * 64;   // 11264 ssim0 blocks
constexpr int NS1 = 8 * 6 * 64;     //  3072 ssim1 blocks
constexpr int NS2 = 4 * 3 * 64;     //   768 ssim2 blocks

static __device__ __forceinline__ double wred(double v) {
#pragma unroll
    for (int off = 32; off > 0; off >>= 1) v += __shfl_down(v, off, 64);
    return v;
}

static __device__ __forceinline__ float readlane_f(float v, int l) {
    return __int_as_float(__builtin_amdgcn_readlane(__float_as_int(v), l));
}
static __device__ __forceinline__ float firstlane_f(float v) {
    return __int_as_float(__builtin_amdgcn_readfirstlane(__float_as_int(v)));
}

// Gaussian window (normalized), computed cooperatively, landed in SGPRs.
template <int K>
static __device__ __forceinline__ void gauss_uni(float sigma, float* g) {
    const int lane = threadIdx.x & 63;
    const int d = lane - K / 2;
    const float inv2s2 = 1.0f / (2.0f * sigma * sigma);
    float e = (lane < K) ? __expf(-(float)(d * d) * inv2s2) : 0.0f;
    float s = e;
#pragma unroll
    for (int off = 8; off > 0; off >>= 1) s += __shfl_down(s, off, 16);
    const float inv = 1.0f / __shfl(s, 0, 64);
#pragma unroll
    for (int k = 0; k < K; ++k) g[k] = firstlane_f(readlane_f(e, k) * inv);
}

// ---------------- fused separable SSIM for one 16x64 output tile ------------
// pl: LDS, 5 planes of [16][80] floats (SoA). red: LDS, 3x4 doubles.

template <int KH, int KW, int H, int W, int Wout, bool DO_L2>
static __device__ void ssim_scale(const float* __restrict__ X,
                                  const float* __restrict__ Y,
                                  int bx, int by, int bz,
                                  float* __restrict__ pl,
                                  double* __restrict__ red,
                                  double* __restrict__ p_lcs,
                                  double* __restrict__ p_cs,
                                  double* __restrict__ p_l2)
{
    constexpr int TH = 16, TW = 64, CG = 20, LC = 80;
    constexpr int PADH = KH / 2, PADW = KW / 2, OFF = 8 - PADW;
    constexpr int PLSTRIDE = TH * LC;   // floats per plane

    const int tid = threadIdx.x;
    const int i0 = by * TH, j0 = bx * TW;
    const float* Xb = X + (size_t)bz * H * W;
    const float* Yb = Y + (size_t)bz * H * W;

    float gh[KH], gw[KW];
    gauss_uni<KH>(1.5f, gh);
    gauss_uni<KW>(1.5f * (float)KW / (float)KH, gw);

    double l2 = 0.0;
    const bool rowsafe = (i0 >= PADH) && (i0 + TH - 1 + PADH < H);

    // ---- phase 1: vertical gaussian of {x, y, xx, yy, xy} -> LDS planes ----
    for (int t = tid; t < TH * CG; t += 256) {
        const int r  = t / CG;
        const int cg = t - r * CG;
        const int cc = j0 - 8 + 4 * cg;
        const int gr = i0 + r;
        float mx0=0,mx1=0,mx2=0,mx3=0, my0=0,my1=0,my2=0,my3=0;
        float xx0=0,xx1=0,xx2=0,xx3=0, yy0=0,yy1=0,yy2=0,yy3=0;
        float xy0=0,xy1=0,xy2=0,xy3=0;
        const bool colsafe = (cc >= 0) && (cc + 3 < W);

        if (rowsafe && colsafe) {
            const float* xp = Xb + (size_t)(gr - PADH) * W + cc;
            const float* yp = Yb + (size_t)(gr - PADH) * W + cc;
#pragma unroll
            for (int k = 0; k < KH; ++k) {
                const float4 xv = *(const float4*)(xp + (size_t)k * W);
                const float4 yv = *(const float4*)(yp + (size_t)k * W);
                const float g = gh[k];
                const float tx0=g*xv.x, tx1=g*xv.y, tx2=g*xv.z, tx3=g*xv.w;
                const float ty0=g*yv.x, ty1=g*yv.y, ty2=g*yv.z, ty3=g*yv.w;
                mx0+=tx0; mx1+=tx1; mx2+=tx2; mx3+=tx3;
                my0+=ty0; my1+=ty1; my2+=ty2; my3+=ty3;
                xx0=fmaf(tx0,xv.x,xx0); xx1=fmaf(tx1,xv.y,xx1);
                xx2=fmaf(tx2,xv.z,xx2); xx3=fmaf(tx3,xv.w,xx3);
                yy0=fmaf(ty0,yv.x,yy0); yy1=fmaf(ty1,yv.y,yy1);
                yy2=fmaf(ty2,yv.z,yy2); yy3=fmaf(ty3,yv.w,yy3);
                xy0=fmaf(tx0,yv.x,xy0); xy1=fmaf(tx1,yv.y,xy1);
                xy2=fmaf(tx2,yv.z,xy2); xy3=fmaf(tx3,yv.w,xy3);
                if (DO_L2 && k == PADH) {
                    if (cg >= 2 && cg < 18) {
                        const float d0=xv.x-yv.x, d1=xv.y-yv.y;
                        const float d2=xv.z-yv.z, d3=xv.w-yv.w;
                        l2 += (double)(((d0*d0)+(d1*d1))+((d2*d2)+(d3*d3)));
                    }
                }
            }
        } else {
#pragma unroll
            for (int k = 0; k < KH; ++k) {
                const int rr = gr - PADH + k;
                if ((unsigned)rr >= (unsigned)H) continue;
                const float* xr = Xb + (size_t)rr * W;
                const float* yr = Yb + (size_t)rr * W;
                float xa[4], ya[4];
#pragma unroll
                for (int i = 0; i < 4; ++i) {
                    const bool ok = ((unsigned)(cc + i) < (unsigned)W);
                    xa[i] = ok ? xr[cc + i] : 0.f;
                    ya[i] = ok ? yr[cc + i] : 0.f;
                }
                const float g = gh[k];
                const float tx0=g*xa[0], tx1=g*xa[1], tx2=g*xa[2], tx3=g*xa[3];
                const float ty0=g*ya[0], ty1=g*ya[1], ty2=g*ya[2], ty3=g*ya[3];
                mx0+=tx0; mx1+=tx1; mx2+=tx2; mx3+=tx3;
                my0+=ty0; my1+=ty1; my2+=ty2; my3+=ty3;
                xx0=fmaf(tx0,xa[0],xx0); xx1=fmaf(tx1,xa[1],xx1);
                xx2=fmaf(tx2,xa[2],xx2); xx3=fmaf(tx3,xa[3],xx3);
                yy0=fmaf(ty0,ya[0],yy0); yy1=fmaf(ty1,ya[1],yy1);
                yy2=fmaf(ty2,ya[2],yy2); yy3=fmaf(ty3,ya[3],yy3);
                xy0=fmaf(tx0,ya[0],xy0); xy1=fmaf(tx1,ya[1],xy1);
                xy2=fmaf(tx2,ya[2],xy2); xy3=fmaf(tx3,ya[3],xy3);
                if (DO_L2 && k == PADH) {
                    if (cg >= 2 && cg < 18) {
                        const float d0=xa[0]-ya[0], d1=xa[1]-ya[1];
                        const float d2=xa[2]-ya[2], d3=xa[3]-ya[3];
                        l2 += (double)(((d0*d0)+(d1*d1))+((d2*d2)+(d3*d3)));
                    }
                }
            }
        }
        float* base = pl + r * LC + 4 * cg;
        *(float4*)(base + 0 * PLSTRIDE) = make_float4(mx0, mx1, mx2, mx3);
        *(float4*)(base + 1 * PLSTRIDE) = make_float4(my0, my1, my2, my3);
        *(float4*)(base + 2 * PLSTRIDE) = make_float4(xx0, xx1, xx2, xx3);
        *(float4*)(base + 3 * PLSTRIDE) = make_float4(yy0, yy1, yy2, yy3);
        *(float4*)(base + 4 * PLSTRIDE) = make_float4(xy0, xy1, xy2, xy3);
    }
    __syncthreads();

    // ---- phase 2: horizontal gaussian via ds_read_b128, 4 cols/thread ------
    const int tc = tid & 15;
    const int ti = tid >> 4;
    float am[5][4];
#pragma unroll
    for (int m = 0; m < 5; ++m) {
        float v[20];
        const float* src = pl + m * PLSTRIDE + ti * LC + 4 * tc;
#pragma unroll
        for (int q = 0; q < 5; ++q) {
            const float4 t4 = *(const float4*)(src + 4 * q);
            v[4*q+0]=t4.x; v[4*q+1]=t4.y; v[4*q+2]=t4.z; v[4*q+3]=t4.w;
        }
#pragma unroll
        for (int j = 0; j < 4; ++j) {
            float s = 0.f;
#pragma unroll
            for (int k = 0; k < KW; ++k) s = fmaf(gw[k], v[OFF + j + k], s);
            am[m][j] = s;
        }
    }

    double lcs = 0.0, cs = 0.0;
    const int gi  = i0 + ti;
    const int gj0 = j0 + 4 * tc;
    if (gi < H) {
#pragma unroll
        for (int j = 0; j < 4; ++j) {
            if (gj0 + j < Wout) {
                const float mxv = am[0][j], myv = am[1][j];
                const float mx2 = mxv*mxv, my2 = myv*myv, mxy = mxv*myv;
                const float vx = am[2][j] - mx2, vy = am[3][j] - my2;
                const float vxy = am[4][j] - mxy;
                const float lv = __fdividef(fmaf(2.f, mxy, 1e-4f), (mx2 + my2) + 1e-4f);
                const float cv = __fdividef(fmaf(2.f, vxy, 9e-4f), (vx + vy) + 9e-4f);
                lcs += (double)(lv * cv);
                cs  += (double)cv;
            }
        }
    }

    lcs = wred(lcs);
    cs  = wred(cs);
    double l2r = 0.0;
    if (DO_L2) l2r = wred(l2);
    const int lane = tid & 63, wv = tid >> 6;
    if (lane == 0) {
        red[0 * 4 + wv] = lcs;
        red[1 * 4 + wv] = cs;
        if (DO_L2) red[2 * 4 + wv] = l2r;
    }
    __syncthreads();
    if (tid == 0) {
        *p_lcs = red[0] + red[1] + red[2] + red[3];
        *p_cs  = red[4] + red[5] + red[6] + red[7];
        if (DO_L2) *p_l2 = red[8] + red[9] + red[10] + red[11];
    }
}

// ---------------- kernel A: pool blocks + ssim0 blocks ----------------------

__global__ __launch_bounds__(256, 4)
void kernelA(const float* __restrict__ X, const float* __restrict__ Y,
             float* __restrict__ x1, float* __restrict__ y1,
             float* __restrict__ x2, float* __restrict__ y2,
             double* __restrict__ pA)
{
    __shared__ __align__(16) float pl[5 * 16 * 80];
    __shared__ double red[12];

    const int f = blockIdx.x;
    if (f >= NPOOL) {
        const int g  = f - NPOOL;
        const int bz = g / 176;
        const int r  = g - bz * 176;
        ssim_scale<11, 15, 176, 1008, 1008, true>(
            X, Y, r & 15, r >> 4, bz, pl, red,
            pA + g, pA + NS0 + g, pA + 2 * NS0 + g);
        return;
    }
    // pool path: x2 point per task; produces x1 (2x2) + x2 (4x4) + y analogs
    constexpr int N2 = 64 * 44 * 252;
    for (int e = f * 256 + threadIdx.x; e < N2; e += NPOOL * 256) {
        const int c2 = e % 252;
        const int t  = e / 252;
        const int r2 = t % 44;
        const int b  = t / 44;
        const size_t ib = ((size_t)b * 176 + 4 * (size_t)r2) * 1008 + 4 * c2;
        const float4 xa = *(const float4*)(X + ib);
        const float4 xb4 = *(const float4*)(X + ib + 1008);
        const float4 xc = *(const float4*)(X + ib + 2016);
        const float4 xd = *(const float4*)(X + ib + 3024);
        const float4 ya = *(const float4*)(Y + ib);
        const float4 yb4 = *(const float4*)(Y + ib + 1008);
        const float4 yc = *(const float4*)(Y + ib + 2016);
        const float4 yd = *(const float4*)(Y + ib + 3024);
        const float px00 = 0.25f * ((xa.x + xa.y) + (xb4.x + xb4.y));
        const float px01 = 0.25f * ((xa.z + xa.w) + (xb4.z + xb4.w));
        const float px10 = 0.25f * ((xc.x + xc.y) + (xd.x + xd.y));
        const float px11 = 0.25f * ((xc.z + xc.w) + (xd.z + xd.w));
        const float py00 = 0.25f * ((ya.x + ya.y) + (yb4.x + yb4.y));
        const float py01 = 0.25f * ((ya.z + ya.w) + (yb4.z + yb4.w));
        const float py10 = 0.25f * ((yc.x + yc.y) + (yd.x + yd.y));
        const float py11 = 0.25f * ((yc.z + yc.w) + (yd.z + yd.w));
        const size_t o1 = ((size_t)b * 88 + 2 * (size_t)r2) * 504 + 2 * c2;
        *(float2*)(x1 + o1)       = make_float2(px00, px01);
        *(float2*)(x1 + o1 + 504) = make_float2(px10, px11);
        *(float2*)(y1 + o1)       = make_float2(py00, py01);
        *(float2*)(y1 + o1 + 504) = make_float2(py10, py11);
        const size_t o2 = ((size_t)b * 44 + r2) * 252 + c2;
        x2[o2] = 0.25f * ((px00 + px01) + (px10 + px11));
        y2[o2] = 0.25f * ((py00 + py01) + (py10 + py11));
    }
}

// ---------------- kernel B: ssim1 + ssim2 -----------------------------------

__global__ __launch_bounds__(256, 4)
void kernelB(const float* __restrict__ x1, const float* __restrict__ y1,
             const float* __restrict__ x2, const float* __restrict__ y2,
             double* __restrict__ pB)
{
    __shared__ __align__(16) float pl[5 * 16 * 80];
    __shared__ double red[12];

    const int f = blockIdx.x;
    if (f < NS1) {
        const int bz = f / 48;
        const int r  = f - bz * 48;
        ssim_scale<9, 12, 88, 504, 505, false>(
            x1, y1, r & 7, r >> 3, bz, pl, red,
            pB + f, pB + NS1 + f, nullptr);
    } else {
        const int g  = f - NS1;
        const int bz = g / 12;
        const int r  = g - bz * 12;
        ssim_scale<7, 10, 44, 252, 253, false>(
            x2, y2, r & 3, r >> 2, bz, pl, red,
            pB + 2 * NS1 + g, pB + 2 * NS1 + NS2 + g, nullptr);
    }
}

// ---------------- kernel C: final reduce + formula --------------------------

__global__ __launch_bounds__(256)
void kernelC(const double* __restrict__ pA, const double* __restrict__ pB,
             float* __restrict__ out)
{
    const int tid = threadIdx.x;
    double a0=0, a1=0, a2=0, a3=0, a4=0, a5=0, a6=0;
    for (int i = tid; i < NS0; i += 256) {
        a0 += pA[i];                // lcs0 (unused in formula)
        a1 += pA[NS0 + i];          // cs0
        a2 += pA[2 * NS0 + i];      // l2
    }
    for (int i = tid; i < NS1; i += 256) {
        a3 += pB[i];                // lcs1 (unused)
        a4 += pB[NS1 + i];          // cs1
    }
    for (int i = tid; i < NS2; i += 256) {
        a5 += pB[2 * NS1 + i];              // lcs2
        a6 += pB[2 * NS1 + NS2 + i];        // cs2 (unused)
    }
    __shared__ double red[7][4];
    double v[7] = {a0, a1, a2, a3, a4, a5, a6};
    const int lane = tid & 63, wv = tid >> 6;
#pragma unroll
    for (int s = 0; s < 7; ++s) {
        const double r = wred(v[s]);
        if (lane == 0) red[s][wv] = r;
    }
    __syncthreads();
    if (tid == 0) {
        double a[7];
#pragma unroll
        for (int s = 0; s < 7; ++s) a[s] = red[s][0] + red[s][1] + red[s][2] + red[s][3];
        const double NE0 = 64.0 * 176.0 * 1008.0;
        const double NE1 = 64.0 * 88.0  * 505.0;
        const double NE2 = 64.0 * 44.0  * 253.0;
        const double l2  = a[2] / NE0;
        const double cs0 = a[1] / NE0;
        const double cs1 = a[4] / NE1;
        const double s2  = a[5] / NE2;
        const double wsum = 0.0448 + 0.2856 + 0.3001;
        const double w0 = 0.0448 / wsum, w1 = 0.2856 / wsum, w2 = 0.3001 / wsum;
        const double ms = pow(cs0, w0) * pow(cs1, w1) * pow(s2, w2);
        const double ssim_loss = 1.0 - ms;
        const double total = 0.3 * l2 + 0.7 * ssim_loss;
        out[0] = (float)total;
        out[1] = (float)l2;
        out[2] = (float)ssim_loss;
    }
}

// ---------------- launch ----------------------------------------------------

extern "C" void kernel_launch(void* const* d_in, const int* in_sizes, int n_in,
                              void* d_out, int out_size, void* d_ws, size_t ws_size,
                              hipStream_t stream)
{
    (void)in_sizes; (void)n_in; (void)out_size; (void)ws_size;

    const float* X = (const float*)d_in[0];
    const float* Y = (const float*)d_in[1];
    float* out = (float*)d_out;

    constexpr int n1 = 64 * 88 * 504;   // 2,838,528
    constexpr int n2 = 64 * 44 * 252;   //   709,632

    double* pA = (double*)d_ws;                    // 3*NS0 doubles
    double* pB = pA + 3 * NS0;                     // 2*NS1 + 2*NS2 doubles
    float* x1 = (float*)(pB + 2 * NS1 + 2 * NS2);
    float* y1 = x1 + n1;
    float* x2 = y1 + n1;
    float* y2 = x2 + n2;

    kernelA<<<NPOOL + NS0, 256, 0, stream>>>(X, Y, x1, y1, x2, y2, pA);
    kernelB<<<NS1 + NS2, 256, 0, stream>>>(x1, y1, x2, y2, pB);
    kernelC<<<1, 256, 0, stream>>>(pA, pB, out);
}